// Round 12
// baseline (309.925 us; speedup 1.0000x reference)
//
#include <hip/hip_runtime.h>
#include <stdint.h>

// ---------------------------------------------------------------------------
// CausalSelfAttention: x[4,2048,1024] fp32 -> out fp32
// bf16 MFMA, fp32 accum.
// R19: attn DE-STAGED (m169/m170 pattern): K/V fragments read DIRECTLY from
//      global (L2-resident: per XCD only bh≡xcd mod 8 -> 8 heads x 512KB =
//      4MB = L2). Deletes ALL barriers, ALL LDS staging/reads, prefetch regs.
//      Waves free-run; compiler pipelines loads with counted vmcnt across the
//      unrolled tile loops. Inner math identical to R18 (swapped-QK 32x32,
//      permlane32_swap P-exchange, VALU row-sum) — proven correct.
//      Grid stays 512 paired (bh mod 8 = XCD pinning is the L2 mechanism).
//      GEMMs unchanged from R13 (BK=64 + XOR swizzle + T1 grid swizzle).
// (R20 resubmit: R19 bench was "container failed twice" — infra, not kernel.)
// ---------------------------------------------------------------------------

typedef float  floatx4  __attribute__((ext_vector_type(4)));
typedef float  f32x16   __attribute__((ext_vector_type(16)));
typedef __bf16 bf16x8   __attribute__((ext_vector_type(8)));
typedef __bf16 bf16x4   __attribute__((ext_vector_type(4)));
typedef unsigned int u32;
typedef u32    u32x4    __attribute__((ext_vector_type(4)));

#define AS1 __attribute__((address_space(1)))
#define AS3 __attribute__((address_space(3)))

__device__ __forceinline__ void gload_lds16(const void* g, void* l) {
    __builtin_amdgcn_global_load_lds((AS1 void*)(uintptr_t)g,
                                     (AS3 void*)(uintptr_t)l, 16, 0, 0);
}

#if __has_builtin(__builtin_amdgcn_exp2f)
#define EXP2F(x) __builtin_amdgcn_exp2f(x)
#else
#define EXP2F(x) exp2f(x)
#endif

// pack two fp32 -> one u32 of two bf16 (lo, hi)
__device__ __forceinline__ u32 pkbf(float lo, float hi) {
    union { __bf16 h[2]; u32 u; } x;
    x.h[0] = (__bf16)lo; x.h[1] = (__bf16)hi;
    return x.u;
}

// v_permlane32_swap_b32: a' = [a_lo, b_lo], b' = [a_hi, b_hi]
__device__ __forceinline__ void plswap(u32& a, u32& b) {
    asm volatile("v_permlane32_swap_b32 %0, %1" : "+v"(a), "+v"(b));
}

#define LOG2E 1.44269504088896340736f
#define ATT_SC (0.125f * LOG2E)   // softmax scale folded into Q at GEMM1
#define MASK_NEG (-3.0e4f)        // exp2(-3e4) == 0, safely finite

static constexpr int Bn = 4, Tn = 2048, Cn = 1024, Hn = 16, DKn = 64;
static constexpr int BT = Bn * Tn;          // 8192
static constexpr int N_QKV = 3 * Cn;        // 3072

// ------------------------- cast / transpose kernels ------------------------

__global__ void cast_x_kernel(const float* __restrict__ x, __bf16* __restrict__ xb, int n) {
    int i = (blockIdx.x * blockDim.x + threadIdx.x) * 4;
    if (i < n) {
        float4 v = *(const float4*)(x + i);
        bf16x4 o;
        o[0] = (__bf16)v.x; o[1] = (__bf16)v.y; o[2] = (__bf16)v.z; o[3] = (__bf16)v.w;
        *(bf16x4*)(xb + i) = o;
    }
}

// W [R][C] fp32 -> WT [C][R] bf16
__global__ void transpose_cast_kernel(const float* __restrict__ W, __bf16* __restrict__ WT,
                                      int R, int C) {
    __shared__ float tile[32][33];
    int tx = threadIdx.x & 31, ty = threadIdx.x >> 5;  // 32 x 8
    int r0 = blockIdx.y * 32, c0 = blockIdx.x * 32;
#pragma unroll
    for (int i = 0; i < 4; i++)
        tile[ty + i * 8][tx] = W[(size_t)(r0 + ty + i * 8) * C + c0 + tx];
    __syncthreads();
#pragma unroll
    for (int i = 0; i < 4; i++)
        WT[(size_t)(c0 + ty + i * 8) * R + r0 + tx] = (__bf16)tile[tx][ty + i * 8];
}

// T1: bijective XCD-aware remap of the flattened block id (nwg % 8 == 0).
__device__ __forceinline__ void xcd_swizzle(int gx, int* bn, int* bm) {
    int flat = blockIdx.y * gx + blockIdx.x;
    int nwg = gx * gridDim.y;
    int cpx = nwg >> 3;
    int swz = (flat & 7) * cpx + (flat >> 3);
    *bm = swz / gx;
    *bn = swz - *bm * gx;
}

// ------------------------------- GEMM 1 ------------------------------------
__global__ __launch_bounds__(256) void gemm_qkv_kernel(
    const __bf16* __restrict__ A, const __bf16* __restrict__ Bt,
    const float* __restrict__ bias,
    __bf16* __restrict__ Qo, __bf16* __restrict__ Ko, __bf16* __restrict__ Vo) {
    const int K = 1024;
    __shared__ __bf16 Al[128 * 64];
    __shared__ __bf16 Bl[128 * 64];
    int tid = threadIdx.x, w = tid >> 6, lane = tid & 63;
    int lq = lane >> 4, l16 = lane & 15;
    int bm, bn;
    xcd_swizzle(gridDim.x, &bn, &bm);
    int wm = w & 1, wn = w >> 1;  // 2x2 waves -> 64x64 each

    int srow = lane >> 3;                 // row within 8-row group
    int scb  = (lane & 7) ^ (srow & 7);   // pre-swizzled global col-block
    const __bf16* Ag = A + (size_t)(bm * 128 + w * 32 + srow) * K + scb * 8;
    const __bf16* Bg = Bt + (size_t)(bn * 128 + w * 32 + srow) * K + scb * 8;
    __bf16* AlW = Al + w * 32 * 64;
    __bf16* BlW = Bl + w * 32 * 64;

    const int co0 = ((0 * 4 + lq) ^ (l16 & 7)) * 8;
    const int co1 = ((1 * 4 + lq) ^ (l16 & 7)) * 8;

    floatx4 acc[4][4] = {};
    for (int k0 = 0; k0 < K; k0 += 64) {
        __syncthreads();
#pragma unroll
        for (int c = 0; c < 4; c++) {
            gload_lds16(Ag + k0 + (size_t)c * 8 * K, AlW + c * 8 * 64);
            gload_lds16(Bg + k0 + (size_t)c * 8 * K, BlW + c * 8 * 64);
        }
        __syncthreads();
#pragma unroll
        for (int ks = 0; ks < 2; ks++) {
            const int co = ks ? co1 : co0;
            bf16x8 af[4], bf[4];
#pragma unroll
            for (int i = 0; i < 4; i++)
                af[i] = *(const bf16x8*)&Al[(wm * 64 + i * 16 + l16) * 64 + co];
#pragma unroll
            for (int i = 0; i < 4; i++)
                bf[i] = *(const bf16x8*)&Bl[(wn * 64 + i * 16 + l16) * 64 + co];
#pragma unroll
            for (int mt = 0; mt < 4; mt++)
#pragma unroll
                for (int nt = 0; nt < 4; nt++)
                    acc[mt][nt] = __builtin_amdgcn_mfma_f32_16x16x32_bf16(
                        af[mt], bf[nt], acc[mt][nt], 0, 0, 0);
        }
    }
#pragma unroll
    for (int nt = 0; nt < 4; nt++) {
        int gbase = bn * 128 + wn * 64 + nt * 16;
        int gcol = gbase + l16;
        int which = gbase >> 10;
        float bv = bias[gcol];
        if (which == 2) {
            int hh = (gbase - 2048) >> 6;
            int dd = ((gbase - 2048) & 63) + l16;
#pragma unroll
            for (int mt = 0; mt < 4; mt++) {
                int growb = bm * 128 + wm * 64 + mt * 16 + lq * 4;
                int bb = growb >> 11, tt = growb & 2047;
                bf16x4 v4;
#pragma unroll
                for (int r = 0; r < 4; r++) v4[r] = (__bf16)(acc[mt][nt][r] + bv);
                *(bf16x4*)&Vo[((size_t)(bb * 16 + hh) * 64 + dd) * 2048 + tt] = v4;
            }
        } else {
            int rem = gbase & 1023;
            int hh = rem >> 6, dd = (rem & 63) + l16;
            __bf16* dst = (which == 0) ? Qo : Ko;
            float scl = (which == 0) ? ATT_SC : 1.0f;
#pragma unroll
            for (int mt = 0; mt < 4; mt++) {
#pragma unroll
                for (int r = 0; r < 4; r++) {
                    int grow = bm * 128 + wm * 64 + mt * 16 + lq * 4 + r;
                    int bb = grow >> 11, tt = grow & 2047;
                    dst[((size_t)(bb * 16 + hh) * 2048 + tt) * 64 + dd] =
                        (__bf16)((acc[mt][nt][r] + bv) * scl);
                }
            }
        }
    }
}

// ------------------------------- GEMM 2 ------------------------------------
__global__ __launch_bounds__(256) void gemm_proj_kernel(
    const __bf16* __restrict__ A, const __bf16* __restrict__ Bt,
    const float* __restrict__ bias, float* __restrict__ out) {
    const int K = 1024;
    __shared__ __bf16 Al[128 * 64];
    __shared__ __bf16 Bl[128 * 64];
    int tid = threadIdx.x, w = tid >> 6, lane = tid & 63;
    int lq = lane >> 4, l16 = lane & 15;
    int bm, bn;
    xcd_swizzle(gridDim.x, &bn, &bm);
    int wm = w & 1, wn = w >> 1;

    int srow = lane >> 3;
    int scb  = (lane & 7) ^ (srow & 7);
    const __bf16* Ag = A + (size_t)(bm * 128 + w * 32 + srow) * K + scb * 8;
    const __bf16* Bg = Bt + (size_t)(bn * 128 + w * 32 + srow) * K + scb * 8;
    __bf16* AlW = Al + w * 32 * 64;
    __bf16* BlW = Bl + w * 32 * 64;

    const int co0 = ((0 * 4 + lq) ^ (l16 & 7)) * 8;
    const int co1 = ((1 * 4 + lq) ^ (l16 & 7)) * 8;

    floatx4 acc[4][4] = {};
    for (int k0 = 0; k0 < K; k0 += 64) {
        __syncthreads();
#pragma unroll
        for (int c = 0; c < 4; c++) {
            gload_lds16(Ag + k0 + (size_t)c * 8 * K, AlW + c * 8 * 64);
            gload_lds16(Bg + k0 + (size_t)c * 8 * K, BlW + c * 8 * 64);
        }
        __syncthreads();
#pragma unroll
        for (int ks = 0; ks < 2; ks++) {
            const int co = ks ? co1 : co0;
            bf16x8 af[4], bf[4];
#pragma unroll
            for (int i = 0; i < 4; i++)
                af[i] = *(const bf16x8*)&Al[(wm * 64 + i * 16 + l16) * 64 + co];
#pragma unroll
            for (int i = 0; i < 4; i++)
                bf[i] = *(const bf16x8*)&Bl[(wn * 64 + i * 16 + l16) * 64 + co];
#pragma unroll
            for (int mt = 0; mt < 4; mt++)
#pragma unroll
                for (int nt = 0; nt < 4; nt++)
                    acc[mt][nt] = __builtin_amdgcn_mfma_f32_16x16x32_bf16(
                        af[mt], bf[nt], acc[mt][nt], 0, 0, 0);
        }
    }
#pragma unroll
    for (int nt = 0; nt < 4; nt++) {
        int gcol = bn * 128 + wn * 64 + nt * 16 + l16;
        float bv = bias[gcol];
#pragma unroll
        for (int mt = 0; mt < 4; mt++) {
#pragma unroll
            for (int r = 0; r < 4; r++) {
                int grow = bm * 128 + wm * 64 + mt * 16 + lq * 4 + r;
                out[(size_t)grow * 1024 + gcol] = acc[mt][nt][r] + bv;
            }
        }
    }
}

// ---------------------------- flash attention ------------------------------
// grid: flat 512, block 256 (4 waves). Block bid: bh = bid&63, q-tile PAIR
// (pr, 15-pr) sequential (uniform 17 k-tile units/block). NO LDS, NO
// barriers: K/V fragments read directly from global (per-XCD L2-resident:
// bid mod 8 == bh mod 8 pins the 8-head 4MB working set to one L2).
// 32x32x16 MFMA, swapped QK (S^T = K·Q^T): lane holds P[key][q=l32];
// P hi/lo exchange via v_permlane32_swap_b32; row-sum = lane-local VALU
// + one __shfl_xor(rs,32) per segment. Q pre-scaled so p = exp2(s).
__global__ __launch_bounds__(256) void attn_kernel(
    const __bf16* __restrict__ Q, const __bf16* __restrict__ K,
    const __bf16* __restrict__ Vt, __bf16* __restrict__ Y) {
    const int bid = blockIdx.x;
    const int pr = bid >> 6, bh = bid & 63;
    const int b = bh >> 4, h = bh & 15;
    int tid = threadIdx.x, w = tid >> 6, lane = tid & 63;
    int l32 = lane & 31, hi = lane >> 5;

    const __bf16* Qh = Q + (size_t)bh * Tn * DKn;
    const __bf16* Kh = K + (size_t)bh * Tn * DKn;   // [2048 t][64 d]
    const __bf16* Vh = Vt + (size_t)bh * DKn * Tn;  // [64 d][2048 t]

#pragma unroll
    for (int seg = 0; seg < 2; seg++) {
        const int qt = seg ? (15 - pr) : pr;
        const int q0 = qt * 128;
        const int ktmax = qt;  // 128-key tiles 0..qt
        const int qrow = q0 + w * 32 + l32;   // this lane's q (col in S^T)

        // Q fragments: B-operand of swapped QK: B[k=d][col=q=l32]
        bf16x8 qf[4];
#pragma unroll
        for (int ds = 0; ds < 4; ds++)
            qf[ds] = *(const bf16x8*)&Qh[(size_t)qrow * 64 + ds * 16 + hi * 8];

        f32x16 oacc0 = {}, oacc1 = {};  // O^T d-tiles 0,1
        float rs = 0.0f;                // lane-local row-sum (this lane's 16-key half)

        for (int kt = 0; kt <= ktmax; kt++) {
            const int kb = kt * 128;  // key base of this tile

            // four 32-key tiles
#pragma unroll
            for (int ktile = 0; ktile < 4; ktile++) {
                // S^T tile: mfma(A=K, B=Q): rows=key, cols=q. ka direct from L2.
                f32x16 s = {};
#pragma unroll
                for (int ds = 0; ds < 4; ds++) {
                    bf16x8 ka = *(const bf16x8*)&Kh[(size_t)(kb + ktile * 32 + l32) * 64 +
                                                    ds * 16 + hi * 8];
                    s = __builtin_amdgcn_mfma_f32_32x32x16_bf16(ka, qf[ds], s, 0, 0, 0);
                }

                // causal mask on the diagonal 128-key tile
                if (kt == qt) {
                    int kbase = kb + ktile * 32 + 4 * hi;
#pragma unroll
                    for (int r = 0; r < 16; r++) {
                        int key = kbase + (r & 3) + 8 * (r >> 2);
                        if (key > qrow) s[r] = MASK_NEG;
                    }
                }

                // p = exp2(s), packed per reg-group; lane-local row-sum in fp32
                u32 G0a, G0b, G1a, G1b, G2a, G2b, G3a, G3b;
                {
                    float p0 = EXP2F(s[0]),  p1 = EXP2F(s[1]),  p2 = EXP2F(s[2]),  p3 = EXP2F(s[3]);
                    float p4 = EXP2F(s[4]),  p5 = EXP2F(s[5]),  p6 = EXP2F(s[6]),  p7 = EXP2F(s[7]);
                    float p8 = EXP2F(s[8]),  p9 = EXP2F(s[9]),  pa = EXP2F(s[10]), pb_ = EXP2F(s[11]);
                    float pc = EXP2F(s[12]), pd = EXP2F(s[13]), pe = EXP2F(s[14]), pf = EXP2F(s[15]);
                    rs += (((p0 + p1) + (p2 + p3)) + ((p4 + p5) + (p6 + p7))) +
                          (((p8 + p9) + (pa + pb_)) + ((pc + pd) + (pe + pf)));
                    G0a = pkbf(p0, p1);  G0b = pkbf(p2, p3);
                    G1a = pkbf(p4, p5);  G1b = pkbf(p6, p7);
                    G2a = pkbf(p8, p9);  G2b = pkbf(pa, pb_);
                    G3a = pkbf(pc, pd);  G3b = pkbf(pe, pf);
                }

                // PV per 16-key step t: B[k=key][col=q]; va direct from L2.
#pragma unroll
                for (int t = 0; t < 2; t++) {
                    u32 a0 = t ? G2a : G0a, b0 = t ? G3a : G1a;
                    u32 a1 = t ? G2b : G0b, b1 = t ? G3b : G1b;
                    plswap(a0, b0);   // a0 = w0, b0 = w2
                    plswap(a1, b1);   // a1 = w1, b1 = w3
                    u32x4 wv = {a0, a1, b0, b1};
                    bf16x8 pbf = __builtin_bit_cast(bf16x8, wv);

                    int kc = kb + ktile * 32 + t * 16 + hi * 8;  // global key col
                    bf16x8 va0 = *(const bf16x8*)&Vh[(size_t)(0 * 32 + l32) * 2048 + kc];
                    bf16x8 va1 = *(const bf16x8*)&Vh[(size_t)(1 * 32 + l32) * 2048 + kc];
                    oacc0 = __builtin_amdgcn_mfma_f32_32x32x16_bf16(va0, pbf, oacc0, 0, 0, 0);
                    oacc1 = __builtin_amdgcn_mfma_f32_32x32x16_bf16(va1, pbf, oacc1, 0, 0, 0);
                }
            }
        }

        // epilogue: O^T[d][q=l32]; total row-sum = own half + partner half.
        float tot = rs + __shfl_xor(rs, 32);
        float inv = 1.0f / tot;
#pragma unroll
        for (int dt2 = 0; dt2 < 2; dt2++) {
#pragma unroll
            for (int rg = 0; rg < 4; rg++) {
                bf16x4 v4;
#pragma unroll
                for (int e = 0; e < 4; e++) {
                    float o = dt2 ? oacc1[rg * 4 + e] : oacc0[rg * 4 + e];
                    v4[e] = (__bf16)(o * inv);
                }
                int d = dt2 * 32 + 8 * rg + 4 * hi;
                *(bf16x4*)&Y[((size_t)(b * 2048 + qrow)) * 1024 + h * 64 + d] = v4;
            }
        }
    }
}

// ------------------------------- launcher ----------------------------------

extern "C" void kernel_launch(void* const* d_in, const int* in_sizes, int n_in,
                              void* d_out, int out_size, void* d_ws, size_t ws_size,
                              hipStream_t stream) {
    const float* x     = (const float*)d_in[0];
    const float* Wqkv  = (const float*)d_in[1];
    const float* bqkv  = (const float*)d_in[2];
    const float* Wproj = (const float*)d_in[3];
    const float* bproj = (const float*)d_in[4];
    float* out = (float*)d_out;

    __bf16* xb     = (__bf16*)d_ws;                       // 8192*1024
    __bf16* WqkvT  = xb + (size_t)BT * Cn;                // 3072*1024
    __bf16* WprojT = WqkvT + (size_t)N_QKV * Cn;          // 1024*1024
    __bf16* Qb     = WprojT + (size_t)Cn * Cn;            // [b][h][t][64], pre-scaled
    __bf16* Kb     = Qb + (size_t)BT * Cn;                // [b][h][t][64]
    __bf16* Vb     = Kb + (size_t)BT * Cn;                // [b][h][64][t] (transposed)
    __bf16* Yb     = Vb + (size_t)BT * Cn;                // 8192*1024

    int nx = BT * Cn;
    cast_x_kernel<<<(nx / 4 + 255) / 256, 256, 0, stream>>>(x, xb, nx);
    transpose_cast_kernel<<<dim3(N_QKV / 32, Cn / 32), 256, 0, stream>>>(Wqkv, WqkvT, Cn, N_QKV);
    transpose_cast_kernel<<<dim3(Cn / 32, Cn / 32), 256, 0, stream>>>(Wproj, WprojT, Cn, Cn);

    gemm_qkv_kernel<<<dim3(N_QKV / 128, BT / 128), 256, 0, stream>>>(
        xb, WqkvT, bqkv, Qb, Kb, Vb);

    attn_kernel<<<dim3(512), 256, 0, stream>>>(Qb, Kb, Vb, Yb);

    gemm_proj_kernel<<<dim3(Cn / 128, BT / 128), 256, 0, stream>>>(
        Yb, WprojT, bproj, out);
}

// Round 13
// 265.974 us; speedup vs baseline: 1.1652x; 1.1652x over previous
//
#include <hip/hip_runtime.h>
#include <stdint.h>

// ---------------------------------------------------------------------------
// CausalSelfAttention: x[4,2048,1024] fp32 -> out fp32
// bf16 MFMA, fp32 accum.
// R21: attn = R18 structure (LDS staging IS the latency amortizer — R19's
//      de-staging doubled dur via L2-latency on every operand) + MERGED
//      segment pair: one k-loop over tiles 0..15-pr; every staged tile
//      serves seg-B (qt=15-pr), tiles <= pr also serve seg-A (qt=pr) from
//      the SAME ka/va registers. Staging/barriers/LDS-reads -26%, compute
//      unchanged & uniform (17 tile-units/block). permlane32_swap P-exchange
//      + VALU row-sum kept from R18.
//      GEMMs unchanged from R13 (BK=64 + XOR swizzle + T1 grid swizzle).
// ---------------------------------------------------------------------------

typedef float  floatx4  __attribute__((ext_vector_type(4)));
typedef float  f32x16   __attribute__((ext_vector_type(16)));
typedef __bf16 bf16x8   __attribute__((ext_vector_type(8)));
typedef __bf16 bf16x4   __attribute__((ext_vector_type(4)));
typedef unsigned int u32;
typedef u32    u32x4    __attribute__((ext_vector_type(4)));

#define AS1 __attribute__((address_space(1)))
#define AS3 __attribute__((address_space(3)))

__device__ __forceinline__ void gload_lds16(const void* g, void* l) {
    __builtin_amdgcn_global_load_lds((AS1 void*)(uintptr_t)g,
                                     (AS3 void*)(uintptr_t)l, 16, 0, 0);
}

#if __has_builtin(__builtin_amdgcn_exp2f)
#define EXP2F(x) __builtin_amdgcn_exp2f(x)
#else
#define EXP2F(x) exp2f(x)
#endif

// pack two fp32 -> one u32 of two bf16 (lo, hi)
__device__ __forceinline__ u32 pkbf(float lo, float hi) {
    union { __bf16 h[2]; u32 u; } x;
    x.h[0] = (__bf16)lo; x.h[1] = (__bf16)hi;
    return x.u;
}

// v_permlane32_swap_b32: a' = [a_lo, b_lo], b' = [a_hi, b_hi]
__device__ __forceinline__ void plswap(u32& a, u32& b) {
    asm volatile("v_permlane32_swap_b32 %0, %1" : "+v"(a), "+v"(b));
}

#define LOG2E 1.44269504088896340736f
#define ATT_SC (0.125f * LOG2E)   // softmax scale folded into Q at GEMM1
#define MASK_NEG (-3.0e4f)        // exp2(-3e4) == 0, safely finite

static constexpr int Bn = 4, Tn = 2048, Cn = 1024, Hn = 16, DKn = 64;
static constexpr int BT = Bn * Tn;          // 8192
static constexpr int N_QKV = 3 * Cn;        // 3072
static constexpr int KPAD = 66;             // Kl row pad (stride 33 words)
static constexpr int VPAD = 130;            // Vl row pad (stride 65 words)

// ------------------------- cast / transpose kernels ------------------------

__global__ void cast_x_kernel(const float* __restrict__ x, __bf16* __restrict__ xb, int n) {
    int i = (blockIdx.x * blockDim.x + threadIdx.x) * 4;
    if (i < n) {
        float4 v = *(const float4*)(x + i);
        bf16x4 o;
        o[0] = (__bf16)v.x; o[1] = (__bf16)v.y; o[2] = (__bf16)v.z; o[3] = (__bf16)v.w;
        *(bf16x4*)(xb + i) = o;
    }
}

// W [R][C] fp32 -> WT [C][R] bf16
__global__ void transpose_cast_kernel(const float* __restrict__ W, __bf16* __restrict__ WT,
                                      int R, int C) {
    __shared__ float tile[32][33];
    int tx = threadIdx.x & 31, ty = threadIdx.x >> 5;  // 32 x 8
    int r0 = blockIdx.y * 32, c0 = blockIdx.x * 32;
#pragma unroll
    for (int i = 0; i < 4; i++)
        tile[ty + i * 8][tx] = W[(size_t)(r0 + ty + i * 8) * C + c0 + tx];
    __syncthreads();
#pragma unroll
    for (int i = 0; i < 4; i++)
        WT[(size_t)(c0 + ty + i * 8) * R + r0 + tx] = (__bf16)tile[tx][ty + i * 8];
}

// T1: bijective XCD-aware remap of the flattened block id (nwg % 8 == 0).
__device__ __forceinline__ void xcd_swizzle(int gx, int* bn, int* bm) {
    int flat = blockIdx.y * gx + blockIdx.x;
    int nwg = gx * gridDim.y;
    int cpx = nwg >> 3;
    int swz = (flat & 7) * cpx + (flat >> 3);
    *bm = swz / gx;
    *bn = swz - *bm * gx;
}

// ------------------------------- GEMM 1 ------------------------------------
__global__ __launch_bounds__(256) void gemm_qkv_kernel(
    const __bf16* __restrict__ A, const __bf16* __restrict__ Bt,
    const float* __restrict__ bias,
    __bf16* __restrict__ Qo, __bf16* __restrict__ Ko, __bf16* __restrict__ Vo) {
    const int K = 1024;
    __shared__ __bf16 Al[128 * 64];
    __shared__ __bf16 Bl[128 * 64];
    int tid = threadIdx.x, w = tid >> 6, lane = tid & 63;
    int lq = lane >> 4, l16 = lane & 15;
    int bm, bn;
    xcd_swizzle(gridDim.x, &bn, &bm);
    int wm = w & 1, wn = w >> 1;  // 2x2 waves -> 64x64 each

    int srow = lane >> 3;                 // row within 8-row group
    int scb  = (lane & 7) ^ (srow & 7);   // pre-swizzled global col-block
    const __bf16* Ag = A + (size_t)(bm * 128 + w * 32 + srow) * K + scb * 8;
    const __bf16* Bg = Bt + (size_t)(bn * 128 + w * 32 + srow) * K + scb * 8;
    __bf16* AlW = Al + w * 32 * 64;
    __bf16* BlW = Bl + w * 32 * 64;

    const int co0 = ((0 * 4 + lq) ^ (l16 & 7)) * 8;
    const int co1 = ((1 * 4 + lq) ^ (l16 & 7)) * 8;

    floatx4 acc[4][4] = {};
    for (int k0 = 0; k0 < K; k0 += 64) {
        __syncthreads();
#pragma unroll
        for (int c = 0; c < 4; c++) {
            gload_lds16(Ag + k0 + (size_t)c * 8 * K, AlW + c * 8 * 64);
            gload_lds16(Bg + k0 + (size_t)c * 8 * K, BlW + c * 8 * 64);
        }
        __syncthreads();
#pragma unroll
        for (int ks = 0; ks < 2; ks++) {
            const int co = ks ? co1 : co0;
            bf16x8 af[4], bf[4];
#pragma unroll
            for (int i = 0; i < 4; i++)
                af[i] = *(const bf16x8*)&Al[(wm * 64 + i * 16 + l16) * 64 + co];
#pragma unroll
            for (int i = 0; i < 4; i++)
                bf[i] = *(const bf16x8*)&Bl[(wn * 64 + i * 16 + l16) * 64 + co];
#pragma unroll
            for (int mt = 0; mt < 4; mt++)
#pragma unroll
                for (int nt = 0; nt < 4; nt++)
                    acc[mt][nt] = __builtin_amdgcn_mfma_f32_16x16x32_bf16(
                        af[mt], bf[nt], acc[mt][nt], 0, 0, 0);
        }
    }
#pragma unroll
    for (int nt = 0; nt < 4; nt++) {
        int gbase = bn * 128 + wn * 64 + nt * 16;
        int gcol = gbase + l16;
        int which = gbase >> 10;
        float bv = bias[gcol];
        if (which == 2) {
            int hh = (gbase - 2048) >> 6;
            int dd = ((gbase - 2048) & 63) + l16;
#pragma unroll
            for (int mt = 0; mt < 4; mt++) {
                int growb = bm * 128 + wm * 64 + mt * 16 + lq * 4;
                int bb = growb >> 11, tt = growb & 2047;
                bf16x4 v4;
#pragma unroll
                for (int r = 0; r < 4; r++) v4[r] = (__bf16)(acc[mt][nt][r] + bv);
                *(bf16x4*)&Vo[((size_t)(bb * 16 + hh) * 64 + dd) * 2048 + tt] = v4;
            }
        } else {
            int rem = gbase & 1023;
            int hh = rem >> 6, dd = (rem & 63) + l16;
            __bf16* dst = (which == 0) ? Qo : Ko;
            float scl = (which == 0) ? ATT_SC : 1.0f;
#pragma unroll
            for (int mt = 0; mt < 4; mt++) {
#pragma unroll
                for (int r = 0; r < 4; r++) {
                    int grow = bm * 128 + wm * 64 + mt * 16 + lq * 4 + r;
                    int bb = grow >> 11, tt = grow & 2047;
                    dst[((size_t)(bb * 16 + hh) * 2048 + tt) * 64 + dd] =
                        (__bf16)((acc[mt][nt][r] + bv) * scl);
                }
            }
        }
    }
}

// ------------------------------- GEMM 2 ------------------------------------
__global__ __launch_bounds__(256) void gemm_proj_kernel(
    const __bf16* __restrict__ A, const __bf16* __restrict__ Bt,
    const float* __restrict__ bias, float* __restrict__ out) {
    const int K = 1024;
    __shared__ __bf16 Al[128 * 64];
    __shared__ __bf16 Bl[128 * 64];
    int tid = threadIdx.x, w = tid >> 6, lane = tid & 63;
    int lq = lane >> 4, l16 = lane & 15;
    int bm, bn;
    xcd_swizzle(gridDim.x, &bn, &bm);
    int wm = w & 1, wn = w >> 1;

    int srow = lane >> 3;
    int scb  = (lane & 7) ^ (srow & 7);
    const __bf16* Ag = A + (size_t)(bm * 128 + w * 32 + srow) * K + scb * 8;
    const __bf16* Bg = Bt + (size_t)(bn * 128 + w * 32 + srow) * K + scb * 8;
    __bf16* AlW = Al + w * 32 * 64;
    __bf16* BlW = Bl + w * 32 * 64;

    const int co0 = ((0 * 4 + lq) ^ (l16 & 7)) * 8;
    const int co1 = ((1 * 4 + lq) ^ (l16 & 7)) * 8;

    floatx4 acc[4][4] = {};
    for (int k0 = 0; k0 < K; k0 += 64) {
        __syncthreads();
#pragma unroll
        for (int c = 0; c < 4; c++) {
            gload_lds16(Ag + k0 + (size_t)c * 8 * K, AlW + c * 8 * 64);
            gload_lds16(Bg + k0 + (size_t)c * 8 * K, BlW + c * 8 * 64);
        }
        __syncthreads();
#pragma unroll
        for (int ks = 0; ks < 2; ks++) {
            const int co = ks ? co1 : co0;
            bf16x8 af[4], bf[4];
#pragma unroll
            for (int i = 0; i < 4; i++)
                af[i] = *(const bf16x8*)&Al[(wm * 64 + i * 16 + l16) * 64 + co];
#pragma unroll
            for (int i = 0; i < 4; i++)
                bf[i] = *(const bf16x8*)&Bl[(wn * 64 + i * 16 + l16) * 64 + co];
#pragma unroll
            for (int mt = 0; mt < 4; mt++)
#pragma unroll
                for (int nt = 0; nt < 4; nt++)
                    acc[mt][nt] = __builtin_amdgcn_mfma_f32_16x16x32_bf16(
                        af[mt], bf[nt], acc[mt][nt], 0, 0, 0);
        }
    }
#pragma unroll
    for (int nt = 0; nt < 4; nt++) {
        int gcol = bn * 128 + wn * 64 + nt * 16 + l16;
        float bv = bias[gcol];
#pragma unroll
        for (int mt = 0; mt < 4; mt++) {
#pragma unroll
            for (int r = 0; r < 4; r++) {
                int grow = bm * 128 + wm * 64 + mt * 16 + lq * 4 + r;
                out[(size_t)grow * 1024 + gcol] = acc[mt][nt][r] + bv;
            }
        }
    }
}

// ---------------------------- flash attention ------------------------------
// grid: flat 512, block 256 (4 waves). Block bid: bh = bid&63, MERGED q-tile
// pair (qtA=pr, qtB=15-pr): ONE k-loop over staged tiles 0..15-pr; every
// tile serves seg-B, tiles <= pr also serve seg-A from the SAME ka/va regs.
// Staged tiles/block = 16-pr (vs 17 sequential); compute uniform 17 units.
// Two-barrier staging + reg-prefetch. 32x32x16 MFMA swapped QK; permlane
// P-exchange; VALU row-sum. Q pre-scaled so p = exp2(s).
__global__ __launch_bounds__(256) void attn_kernel(
    const __bf16* __restrict__ Q, const __bf16* __restrict__ K,
    const __bf16* __restrict__ Vt, __bf16* __restrict__ Y) {
    const int bid = blockIdx.x;
    const int pr = bid >> 6, bh = bid & 63;
    const int b = bh >> 4, h = bh & 15;
    int tid = threadIdx.x, w = tid >> 6, lane = tid & 63;
    int l32 = lane & 31, hi = lane >> 5;

    const __bf16* Qh = Q + (size_t)bh * Tn * DKn;
    const __bf16* Kh = K + (size_t)bh * Tn * DKn;
    const __bf16* Vh = Vt + (size_t)bh * DKn * Tn;  // [64 d][2048 t]

    __shared__ __bf16 Kl[128 * KPAD];   // [key 0..127][d 0..63]
    __shared__ __bf16 Vl[64 * VPAD];    // [d 0..63][key 0..127]

    int skrow = tid >> 3, sksl = tid & 7;    // K: 8 lanes/row
    int svrow = tid >> 4, svsl = tid & 15;   // V: 16 lanes/row

    const int qtA = pr, qtB = 15 - pr;
    const int NT = qtB + 1;                   // staged tiles 0..NT-1
    const int qrowA = qtA * 128 + w * 32 + l32;
    const int qrowB = qtB * 128 + w * 32 + l32;

    // Q fragments, both segments: B-operand of swapped QK
    bf16x8 qfA[4], qfB[4];
#pragma unroll
    for (int ds = 0; ds < 4; ds++) {
        qfA[ds] = *(const bf16x8*)&Qh[(size_t)qrowA * 64 + ds * 16 + hi * 8];
        qfB[ds] = *(const bf16x8*)&Qh[(size_t)qrowB * 64 + ds * 16 + hi * 8];
    }

    f32x16 oA0 = {}, oA1 = {}, oB0 = {}, oB1 = {};
    float rsA = 0.0f, rsB = 0.0f;

    // prefetch 128-key tile 0
    bf16x8 kr[4], vr[4];
#pragma unroll
    for (int i = 0; i < 4; i++) {
        kr[i] = *(const bf16x8*)&Kh[(size_t)(skrow + i * 32) * 64 + sksl * 8];
        vr[i] = *(const bf16x8*)&Vh[(size_t)(svrow + i * 16) * 2048 + svsl * 8];
    }

    for (int kt = 0; kt < NT; kt++) {
        __syncthreads();  // all waves done reading Kl/Vl from previous iter
#pragma unroll
        for (int i = 0; i < 4; i++) {
            *(bf16x8*)&Kl[(skrow + i * 32) * KPAD + sksl * 8] = kr[i];
            *(bf16x8*)&Vl[(svrow + i * 16) * VPAD + svsl * 8] = vr[i];
        }
        __syncthreads();
        // prefetch next 128-key tile
        if (kt + 1 < NT) {
            int nk = kt + 1;
#pragma unroll
            for (int i = 0; i < 4; i++) {
                kr[i] = *(const bf16x8*)&Kh[(size_t)(nk * 128 + skrow + i * 32) * 64 + sksl * 8];
                vr[i] = *(const bf16x8*)&Vh[(size_t)(svrow + i * 16) * 2048 + nk * 128 + svsl * 8];
            }
        }

        const bool doA = (kt <= qtA);
        const int kb = kt * 128;

        // four 32-key tiles from the staged 128-key tile
#pragma unroll
        for (int ktile = 0; ktile < 4; ktile++) {
            // shared K fragments for both segments
            bf16x8 ka4[4];
#pragma unroll
            for (int ds = 0; ds < 4; ds++)
                ka4[ds] = *(const bf16x8*)&Kl[(ktile * 32 + l32) * KPAD + ds * 16 + hi * 8];

            f32x16 sB = {};
#pragma unroll
            for (int ds = 0; ds < 4; ds++)
                sB = __builtin_amdgcn_mfma_f32_32x32x16_bf16(ka4[ds], qfB[ds], sB, 0, 0, 0);
            f32x16 sA = {};
            if (doA) {
#pragma unroll
                for (int ds = 0; ds < 4; ds++)
                    sA = __builtin_amdgcn_mfma_f32_32x32x16_bf16(ka4[ds], qfA[ds], sA, 0, 0, 0);
            }

            // causal masks (diagonal tiles only)
            if (kt == qtB) {
                int kbase = kb + ktile * 32 + 4 * hi;
#pragma unroll
                for (int r = 0; r < 16; r++) {
                    int key = kbase + (r & 3) + 8 * (r >> 2);
                    if (key > qrowB) sB[r] = MASK_NEG;
                }
            }
            if (doA && kt == qtA) {
                int kbase = kb + ktile * 32 + 4 * hi;
#pragma unroll
                for (int r = 0; r < 16; r++) {
                    int key = kbase + (r & 3) + 8 * (r >> 2);
                    if (key > qrowA) sA[r] = MASK_NEG;
                }
            }

            // p = exp2(s), packed; lane-local fp32 row-sums
            u32 B0a, B0b, B1a, B1b, B2a, B2b, B3a, B3b;
            {
                float p0 = EXP2F(sB[0]),  p1 = EXP2F(sB[1]),  p2 = EXP2F(sB[2]),  p3 = EXP2F(sB[3]);
                float p4 = EXP2F(sB[4]),  p5 = EXP2F(sB[5]),  p6 = EXP2F(sB[6]),  p7 = EXP2F(sB[7]);
                float p8 = EXP2F(sB[8]),  p9 = EXP2F(sB[9]),  pa = EXP2F(sB[10]), pb_ = EXP2F(sB[11]);
                float pc = EXP2F(sB[12]), pd = EXP2F(sB[13]), pe = EXP2F(sB[14]), pf = EXP2F(sB[15]);
                rsB += (((p0 + p1) + (p2 + p3)) + ((p4 + p5) + (p6 + p7))) +
                       (((p8 + p9) + (pa + pb_)) + ((pc + pd) + (pe + pf)));
                B0a = pkbf(p0, p1);  B0b = pkbf(p2, p3);
                B1a = pkbf(p4, p5);  B1b = pkbf(p6, p7);
                B2a = pkbf(p8, p9);  B2b = pkbf(pa, pb_);
                B3a = pkbf(pc, pd);  B3b = pkbf(pe, pf);
            }
            u32 A0a, A0b, A1a, A1b, A2a, A2b, A3a, A3b;
            if (doA) {
                float p0 = EXP2F(sA[0]),  p1 = EXP2F(sA[1]),  p2 = EXP2F(sA[2]),  p3 = EXP2F(sA[3]);
                float p4 = EXP2F(sA[4]),  p5 = EXP2F(sA[5]),  p6 = EXP2F(sA[6]),  p7 = EXP2F(sA[7]);
                float p8 = EXP2F(sA[8]),  p9 = EXP2F(sA[9]),  pa = EXP2F(sA[10]), pb_ = EXP2F(sA[11]);
                float pc = EXP2F(sA[12]), pd = EXP2F(sA[13]), pe = EXP2F(sA[14]), pf = EXP2F(sA[15]);
                rsA += (((p0 + p1) + (p2 + p3)) + ((p4 + p5) + (p6 + p7))) +
                       (((p8 + p9) + (pa + pb_)) + ((pc + pd) + (pe + pf)));
                A0a = pkbf(p0, p1);  A0b = pkbf(p2, p3);
                A1a = pkbf(p4, p5);  A1b = pkbf(p6, p7);
                A2a = pkbf(p8, p9);  A2b = pkbf(pa, pb_);
                A3a = pkbf(pc, pd);  A3b = pkbf(pe, pf);
            }

            // PV per 16-key step t: shared va reads; B always, A when doA.
#pragma unroll
            for (int t = 0; t < 2; t++) {
                int kc = kb + ktile * 32 + t * 16 + hi * 8;  // key col (wave-local tile idx)
                int kcl = ktile * 32 + t * 16 + hi * 8;      // key col in LDS
                bf16x8 va0 = *(const bf16x8*)&Vl[(0 * 32 + l32) * VPAD + kcl];
                bf16x8 va1 = *(const bf16x8*)&Vl[(1 * 32 + l32) * VPAD + kcl];
                (void)kc;

                {
                    u32 a0 = t ? B2a : B0a, b0 = t ? B3a : B1a;
                    u32 a1 = t ? B2b : B0b, b1 = t ? B3b : B1b;
                    plswap(a0, b0);
                    plswap(a1, b1);
                    u32x4 wv = {a0, a1, b0, b1};
                    bf16x8 pbf = __builtin_bit_cast(bf16x8, wv);
                    oB0 = __builtin_amdgcn_mfma_f32_32x32x16_bf16(va0, pbf, oB0, 0, 0, 0);
                    oB1 = __builtin_amdgcn_mfma_f32_32x32x16_bf16(va1, pbf, oB1, 0, 0, 0);
                }
                if (doA) {
                    u32 a0 = t ? A2a : A0a, b0 = t ? A3a : A1a;
                    u32 a1 = t ? A2b : A0b, b1 = t ? A3b : A1b;
                    plswap(a0, b0);
                    plswap(a1, b1);
                    u32x4 wv = {a0, a1, b0, b1};
                    bf16x8 pbf = __builtin_bit_cast(bf16x8, wv);
                    oA0 = __builtin_amdgcn_mfma_f32_32x32x16_bf16(va0, pbf, oA0, 0, 0, 0);
                    oA1 = __builtin_amdgcn_mfma_f32_32x32x16_bf16(va1, pbf, oA1, 0, 0, 0);
                }
            }
        }
    }

    // epilogues: O^T[d][q=l32] for each segment.
    {
        float tot = rsA + __shfl_xor(rsA, 32);
        float inv = 1.0f / tot;
#pragma unroll
        for (int dt2 = 0; dt2 < 2; dt2++) {
#pragma unroll
            for (int rg = 0; rg < 4; rg++) {
                bf16x4 v4;
#pragma unroll
                for (int e = 0; e < 4; e++) {
                    float o = dt2 ? oA1[rg * 4 + e] : oA0[rg * 4 + e];
                    v4[e] = (__bf16)(o * inv);
                }
                int d = dt2 * 32 + 8 * rg + 4 * hi;
                *(bf16x4*)&Y[((size_t)(b * 2048 + qrowA)) * 1024 + h * 64 + d] = v4;
            }
        }
    }
    {
        float tot = rsB + __shfl_xor(rsB, 32);
        float inv = 1.0f / tot;
#pragma unroll
        for (int dt2 = 0; dt2 < 2; dt2++) {
#pragma unroll
            for (int rg = 0; rg < 4; rg++) {
                bf16x4 v4;
#pragma unroll
                for (int e = 0; e < 4; e++) {
                    float o = dt2 ? oB1[rg * 4 + e] : oB0[rg * 4 + e];
                    v4[e] = (__bf16)(o * inv);
                }
                int d = dt2 * 32 + 8 * rg + 4 * hi;
                *(bf16x4*)&Y[((size_t)(b * 2048 + qrowB)) * 1024 + h * 64 + d] = v4;
            }
        }
    }
}

// ------------------------------- launcher ----------------------------------

extern "C" void kernel_launch(void* const* d_in, const int* in_sizes, int n_in,
                              void* d_out, int out_size, void* d_ws, size_t ws_size,
                              hipStream_t stream) {
    const float* x     = (const float*)d_in[0];
    const float* Wqkv  = (const float*)d_in[1];
    const float* bqkv  = (const float*)d_in[2];
    const float* Wproj = (const float*)d_in[3];
    const float* bproj = (const float*)d_in[4];
    float* out = (float*)d_out;

    __bf16* xb     = (__bf16*)d_ws;                       // 8192*1024
    __bf16* WqkvT  = xb + (size_t)BT * Cn;                // 3072*1024
    __bf16* WprojT = WqkvT + (size_t)N_QKV * Cn;          // 1024*1024
    __bf16* Qb     = WprojT + (size_t)Cn * Cn;            // [b][h][t][64], pre-scaled
    __bf16* Kb     = Qb + (size_t)BT * Cn;                // [b][h][t][64]
    __bf16* Vb     = Kb + (size_t)BT * Cn;                // [b][h][64][t] (transposed)
    __bf16* Yb     = Vb + (size_t)BT * Cn;                // 8192*1024

    int nx = BT * Cn;
    cast_x_kernel<<<(nx / 4 + 255) / 256, 256, 0, stream>>>(x, xb, nx);
    transpose_cast_kernel<<<dim3(N_QKV / 32, Cn / 32), 256, 0, stream>>>(Wqkv, WqkvT, Cn, N_QKV);
    transpose_cast_kernel<<<dim3(Cn / 32, Cn / 32), 256, 0, stream>>>(Wproj, WprojT, Cn, Cn);

    gemm_qkv_kernel<<<dim3(N_QKV / 128, BT / 128), 256, 0, stream>>>(
        xb, WqkvT, bqkv, Qb, Kb, Vb);

    attn_kernel<<<dim3(512), 256, 0, stream>>>(Qb, Kb, Vb, Yb);

    gemm_proj_kernel<<<dim3(Cn / 128, BT / 128), 256, 0, stream>>>(
        Yb, WprojT, bproj, out);
}

// Round 14
// 243.245 us; speedup vs baseline: 1.2741x; 1.0934x over previous
//
#include <hip/hip_runtime.h>
#include <stdint.h>

// ---------------------------------------------------------------------------
// CausalSelfAttention: x[4,2048,1024] fp32 -> out fp32
// bf16 MFMA, fp32 accum.
// R22: attn REVERTED to exact R18 (71.1us measured; R21's merged-pair grew
//      VGPR 116->140, occupancy 17.9->11, dur 1.6x — same lesson as R9:
//      structural rewrites that grow per-wave state lose on this kernel).
//      ONE isolated change: T5 s_setprio(1)/(0) around the QK and PV MFMA
//      clusters (m191: +4-7% attn; never isolated on this structure — R9
//      bundled it with a regressing rewrite). Two intrinsic pairs, nothing
//      else touched. GEMMs unchanged from R13 (BK=64 + XOR swizzle + T1).
// ---------------------------------------------------------------------------

typedef float  floatx4  __attribute__((ext_vector_type(4)));
typedef float  f32x16   __attribute__((ext_vector_type(16)));
typedef __bf16 bf16x8   __attribute__((ext_vector_type(8)));
typedef __bf16 bf16x4   __attribute__((ext_vector_type(4)));
typedef unsigned int u32;
typedef u32    u32x4    __attribute__((ext_vector_type(4)));

#define AS1 __attribute__((address_space(1)))
#define AS3 __attribute__((address_space(3)))

__device__ __forceinline__ void gload_lds16(const void* g, void* l) {
    __builtin_amdgcn_global_load_lds((AS1 void*)(uintptr_t)g,
                                     (AS3 void*)(uintptr_t)l, 16, 0, 0);
}

#if __has_builtin(__builtin_amdgcn_exp2f)
#define EXP2F(x) __builtin_amdgcn_exp2f(x)
#else
#define EXP2F(x) exp2f(x)
#endif

// pack two fp32 -> one u32 of two bf16 (lo, hi)
__device__ __forceinline__ u32 pkbf(float lo, float hi) {
    union { __bf16 h[2]; u32 u; } x;
    x.h[0] = (__bf16)lo; x.h[1] = (__bf16)hi;
    return x.u;
}

// v_permlane32_swap_b32: a' = [a_lo, b_lo], b' = [a_hi, b_hi]
__device__ __forceinline__ void plswap(u32& a, u32& b) {
    asm volatile("v_permlane32_swap_b32 %0, %1" : "+v"(a), "+v"(b));
}

#define LOG2E 1.44269504088896340736f
#define ATT_SC (0.125f * LOG2E)   // softmax scale folded into Q at GEMM1
#define MASK_NEG (-3.0e4f)        // exp2(-3e4) == 0, safely finite

static constexpr int Bn = 4, Tn = 2048, Cn = 1024, Hn = 16, DKn = 64;
static constexpr int BT = Bn * Tn;          // 8192
static constexpr int N_QKV = 3 * Cn;        // 3072
static constexpr int KPAD = 66;             // Kl row pad (stride 33 words)
static constexpr int VPAD = 130;            // Vl row pad (stride 65 words)

// ------------------------- cast / transpose kernels ------------------------

__global__ void cast_x_kernel(const float* __restrict__ x, __bf16* __restrict__ xb, int n) {
    int i = (blockIdx.x * blockDim.x + threadIdx.x) * 4;
    if (i < n) {
        float4 v = *(const float4*)(x + i);
        bf16x4 o;
        o[0] = (__bf16)v.x; o[1] = (__bf16)v.y; o[2] = (__bf16)v.z; o[3] = (__bf16)v.w;
        *(bf16x4*)(xb + i) = o;
    }
}

// W [R][C] fp32 -> WT [C][R] bf16
__global__ void transpose_cast_kernel(const float* __restrict__ W, __bf16* __restrict__ WT,
                                      int R, int C) {
    __shared__ float tile[32][33];
    int tx = threadIdx.x & 31, ty = threadIdx.x >> 5;  // 32 x 8
    int r0 = blockIdx.y * 32, c0 = blockIdx.x * 32;
#pragma unroll
    for (int i = 0; i < 4; i++)
        tile[ty + i * 8][tx] = W[(size_t)(r0 + ty + i * 8) * C + c0 + tx];
    __syncthreads();
#pragma unroll
    for (int i = 0; i < 4; i++)
        WT[(size_t)(c0 + ty + i * 8) * R + r0 + tx] = (__bf16)tile[tx][ty + i * 8];
}

// T1: bijective XCD-aware remap of the flattened block id (nwg % 8 == 0).
__device__ __forceinline__ void xcd_swizzle(int gx, int* bn, int* bm) {
    int flat = blockIdx.y * gx + blockIdx.x;
    int nwg = gx * gridDim.y;
    int cpx = nwg >> 3;
    int swz = (flat & 7) * cpx + (flat >> 3);
    *bm = swz / gx;
    *bn = swz - *bm * gx;
}

// ------------------------------- GEMM 1 ------------------------------------
__global__ __launch_bounds__(256) void gemm_qkv_kernel(
    const __bf16* __restrict__ A, const __bf16* __restrict__ Bt,
    const float* __restrict__ bias,
    __bf16* __restrict__ Qo, __bf16* __restrict__ Ko, __bf16* __restrict__ Vo) {
    const int K = 1024;
    __shared__ __bf16 Al[128 * 64];
    __shared__ __bf16 Bl[128 * 64];
    int tid = threadIdx.x, w = tid >> 6, lane = tid & 63;
    int lq = lane >> 4, l16 = lane & 15;
    int bm, bn;
    xcd_swizzle(gridDim.x, &bn, &bm);
    int wm = w & 1, wn = w >> 1;  // 2x2 waves -> 64x64 each

    int srow = lane >> 3;                 // row within 8-row group
    int scb  = (lane & 7) ^ (srow & 7);   // pre-swizzled global col-block
    const __bf16* Ag = A + (size_t)(bm * 128 + w * 32 + srow) * K + scb * 8;
    const __bf16* Bg = Bt + (size_t)(bn * 128 + w * 32 + srow) * K + scb * 8;
    __bf16* AlW = Al + w * 32 * 64;
    __bf16* BlW = Bl + w * 32 * 64;

    const int co0 = ((0 * 4 + lq) ^ (l16 & 7)) * 8;
    const int co1 = ((1 * 4 + lq) ^ (l16 & 7)) * 8;

    floatx4 acc[4][4] = {};
    for (int k0 = 0; k0 < K; k0 += 64) {
        __syncthreads();
#pragma unroll
        for (int c = 0; c < 4; c++) {
            gload_lds16(Ag + k0 + (size_t)c * 8 * K, AlW + c * 8 * 64);
            gload_lds16(Bg + k0 + (size_t)c * 8 * K, BlW + c * 8 * 64);
        }
        __syncthreads();
#pragma unroll
        for (int ks = 0; ks < 2; ks++) {
            const int co = ks ? co1 : co0;
            bf16x8 af[4], bf[4];
#pragma unroll
            for (int i = 0; i < 4; i++)
                af[i] = *(const bf16x8*)&Al[(wm * 64 + i * 16 + l16) * 64 + co];
#pragma unroll
            for (int i = 0; i < 4; i++)
                bf[i] = *(const bf16x8*)&Bl[(wn * 64 + i * 16 + l16) * 64 + co];
#pragma unroll
            for (int mt = 0; mt < 4; mt++)
#pragma unroll
                for (int nt = 0; nt < 4; nt++)
                    acc[mt][nt] = __builtin_amdgcn_mfma_f32_16x16x32_bf16(
                        af[mt], bf[nt], acc[mt][nt], 0, 0, 0);
        }
    }
#pragma unroll
    for (int nt = 0; nt < 4; nt++) {
        int gbase = bn * 128 + wn * 64 + nt * 16;
        int gcol = gbase + l16;
        int which = gbase >> 10;
        float bv = bias[gcol];
        if (which == 2) {
            int hh = (gbase - 2048) >> 6;
            int dd = ((gbase - 2048) & 63) + l16;
#pragma unroll
            for (int mt = 0; mt < 4; mt++) {
                int growb = bm * 128 + wm * 64 + mt * 16 + lq * 4;
                int bb = growb >> 11, tt = growb & 2047;
                bf16x4 v4;
#pragma unroll
                for (int r = 0; r < 4; r++) v4[r] = (__bf16)(acc[mt][nt][r] + bv);
                *(bf16x4*)&Vo[((size_t)(bb * 16 + hh) * 64 + dd) * 2048 + tt] = v4;
            }
        } else {
            int rem = gbase & 1023;
            int hh = rem >> 6, dd = (rem & 63) + l16;
            __bf16* dst = (which == 0) ? Qo : Ko;
            float scl = (which == 0) ? ATT_SC : 1.0f;
#pragma unroll
            for (int mt = 0; mt < 4; mt++) {
#pragma unroll
                for (int r = 0; r < 4; r++) {
                    int grow = bm * 128 + wm * 64 + mt * 16 + lq * 4 + r;
                    int bb = grow >> 11, tt = grow & 2047;
                    dst[((size_t)(bb * 16 + hh) * 2048 + tt) * 64 + dd] =
                        (__bf16)((acc[mt][nt][r] + bv) * scl);
                }
            }
        }
    }
}

// ------------------------------- GEMM 2 ------------------------------------
__global__ __launch_bounds__(256) void gemm_proj_kernel(
    const __bf16* __restrict__ A, const __bf16* __restrict__ Bt,
    const float* __restrict__ bias, float* __restrict__ out) {
    const int K = 1024;
    __shared__ __bf16 Al[128 * 64];
    __shared__ __bf16 Bl[128 * 64];
    int tid = threadIdx.x, w = tid >> 6, lane = tid & 63;
    int lq = lane >> 4, l16 = lane & 15;
    int bm, bn;
    xcd_swizzle(gridDim.x, &bn, &bm);
    int wm = w & 1, wn = w >> 1;

    int srow = lane >> 3;
    int scb  = (lane & 7) ^ (srow & 7);
    const __bf16* Ag = A + (size_t)(bm * 128 + w * 32 + srow) * K + scb * 8;
    const __bf16* Bg = Bt + (size_t)(bn * 128 + w * 32 + srow) * K + scb * 8;
    __bf16* AlW = Al + w * 32 * 64;
    __bf16* BlW = Bl + w * 32 * 64;

    const int co0 = ((0 * 4 + lq) ^ (l16 & 7)) * 8;
    const int co1 = ((1 * 4 + lq) ^ (l16 & 7)) * 8;

    floatx4 acc[4][4] = {};
    for (int k0 = 0; k0 < K; k0 += 64) {
        __syncthreads();
#pragma unroll
        for (int c = 0; c < 4; c++) {
            gload_lds16(Ag + k0 + (size_t)c * 8 * K, AlW + c * 8 * 64);
            gload_lds16(Bg + k0 + (size_t)c * 8 * K, BlW + c * 8 * 64);
        }
        __syncthreads();
#pragma unroll
        for (int ks = 0; ks < 2; ks++) {
            const int co = ks ? co1 : co0;
            bf16x8 af[4], bf[4];
#pragma unroll
            for (int i = 0; i < 4; i++)
                af[i] = *(const bf16x8*)&Al[(wm * 64 + i * 16 + l16) * 64 + co];
#pragma unroll
            for (int i = 0; i < 4; i++)
                bf[i] = *(const bf16x8*)&Bl[(wn * 64 + i * 16 + l16) * 64 + co];
#pragma unroll
            for (int mt = 0; mt < 4; mt++)
#pragma unroll
                for (int nt = 0; nt < 4; nt++)
                    acc[mt][nt] = __builtin_amdgcn_mfma_f32_16x16x32_bf16(
                        af[mt], bf[nt], acc[mt][nt], 0, 0, 0);
        }
    }
#pragma unroll
    for (int nt = 0; nt < 4; nt++) {
        int gcol = bn * 128 + wn * 64 + nt * 16 + l16;
        float bv = bias[gcol];
#pragma unroll
        for (int mt = 0; mt < 4; mt++) {
#pragma unroll
            for (int r = 0; r < 4; r++) {
                int grow = bm * 128 + wm * 64 + mt * 16 + lq * 4 + r;
                out[(size_t)grow * 1024 + gcol] = acc[mt][nt][r] + bv;
            }
        }
    }
}

// ---------------------------- flash attention ------------------------------
// grid: flat 512, block 256 (4 waves). Block bid: bh = bid&63, q-tile PAIR
// (pr, 15-pr) sequential (uniform 17 staged tiles/block). KVBLK=128.
// Two-barrier staging skeleton + reg-prefetch with cross-segment handoff.
// 32x32x16 MFMA, swapped QK (S^T = K·Q^T): lane holds P[key][q=l32].
// permlane32_swap P-exchange; VALU row-sum + __shfl_xor(rs,32).
// R22: s_setprio(1)/(0) around the QK and PV MFMA clusters (T5, m191).
__global__ __launch_bounds__(256) void attn_kernel(
    const __bf16* __restrict__ Q, const __bf16* __restrict__ K,
    const __bf16* __restrict__ Vt, __bf16* __restrict__ Y) {
    const int bid = blockIdx.x;
    const int pr = bid >> 6, bh = bid & 63;
    const int b = bh >> 4, h = bh & 15;
    int tid = threadIdx.x, w = tid >> 6, lane = tid & 63;
    int l32 = lane & 31, hi = lane >> 5;

    const __bf16* Qh = Q + (size_t)bh * Tn * DKn;
    const __bf16* Kh = K + (size_t)bh * Tn * DKn;
    const __bf16* Vh = Vt + (size_t)bh * DKn * Tn;  // [64 d][2048 t]

    __shared__ __bf16 Kl[128 * KPAD];   // [key 0..127][d 0..63]
    __shared__ __bf16 Vl[64 * VPAD];    // [d 0..63][key 0..127]

    int skrow = tid >> 3, sksl = tid & 7;    // K: 8 lanes/row
    int svrow = tid >> 4, svsl = tid & 15;   // V: 16 lanes/row

    // prefetch 128-key tile 0 (shared by both segments' first iteration)
    bf16x8 kr[4], vr[4];
#pragma unroll
    for (int i = 0; i < 4; i++) {
        kr[i] = *(const bf16x8*)&Kh[(size_t)(skrow + i * 32) * 64 + sksl * 8];
        vr[i] = *(const bf16x8*)&Vh[(size_t)(svrow + i * 16) * 2048 + svsl * 8];
    }

#pragma unroll
    for (int seg = 0; seg < 2; seg++) {
        const int qt = seg ? (15 - pr) : pr;
        const int q0 = qt * 128;
        const int ktmax = qt;  // 128-key tiles 0..qt
        const int qrow = q0 + w * 32 + l32;   // this lane's q (col in S^T)

        // Q fragments: B-operand of swapped QK: B[k=d][col=q=l32]
        bf16x8 qf[4];
#pragma unroll
        for (int ds = 0; ds < 4; ds++)
            qf[ds] = *(const bf16x8*)&Qh[(size_t)qrow * 64 + ds * 16 + hi * 8];

        f32x16 oacc0 = {}, oacc1 = {};  // O^T d-tiles 0,1
        float rs = 0.0f;                // lane-local row-sum (this lane's 16-key half)

        for (int kt = 0; kt <= ktmax; kt++) {
            __syncthreads();  // all waves done reading Kl/Vl from previous iter
#pragma unroll
            for (int i = 0; i < 4; i++) {
                *(bf16x8*)&Kl[(skrow + i * 32) * KPAD + sksl * 8] = kr[i];
                *(bf16x8*)&Vl[(svrow + i * 16) * VPAD + svsl * 8] = vr[i];
            }
            __syncthreads();
            // prefetch next tile (next kt, or segment-B tile 0 at boundary)
            if (!(seg == 1 && kt == ktmax)) {
                int nk = (kt < ktmax) ? (kt + 1) : 0;
#pragma unroll
                for (int i = 0; i < 4; i++) {
                    kr[i] = *(const bf16x8*)&Kh[(size_t)(nk * 128 + skrow + i * 32) * 64 + sksl * 8];
                    vr[i] = *(const bf16x8*)&Vh[(size_t)(svrow + i * 16) * 2048 + nk * 128 + svsl * 8];
                }
            }

            // four 32-key tiles from the staged 128-key tile
#pragma unroll
            for (int ktile = 0; ktile < 4; ktile++) {
                // S^T tile: mfma(A=K, B=Q): rows=key, cols=q
                f32x16 s = {};
                __builtin_amdgcn_s_setprio(1);
#pragma unroll
                for (int ds = 0; ds < 4; ds++) {
                    bf16x8 ka = *(const bf16x8*)&Kl[(ktile * 32 + l32) * KPAD +
                                                    ds * 16 + hi * 8];
                    s = __builtin_amdgcn_mfma_f32_32x32x16_bf16(ka, qf[ds], s, 0, 0, 0);
                }
                __builtin_amdgcn_s_setprio(0);

                // causal mask on the diagonal 128-key tile
                if (kt == qt) {
                    int kbase = kt * 128 + ktile * 32 + 4 * hi;
#pragma unroll
                    for (int r = 0; r < 16; r++) {
                        int key = kbase + (r & 3) + 8 * (r >> 2);
                        if (key > qrow) s[r] = MASK_NEG;
                    }
                }

                // p = exp2(s), packed per reg-group; lane-local row-sum in fp32
                u32 G0a, G0b, G1a, G1b, G2a, G2b, G3a, G3b;
                {
                    float p0 = EXP2F(s[0]),  p1 = EXP2F(s[1]),  p2 = EXP2F(s[2]),  p3 = EXP2F(s[3]);
                    float p4 = EXP2F(s[4]),  p5 = EXP2F(s[5]),  p6 = EXP2F(s[6]),  p7 = EXP2F(s[7]);
                    float p8 = EXP2F(s[8]),  p9 = EXP2F(s[9]),  pa = EXP2F(s[10]), pb_ = EXP2F(s[11]);
                    float pc = EXP2F(s[12]), pd = EXP2F(s[13]), pe = EXP2F(s[14]), pf = EXP2F(s[15]);
                    rs += (((p0 + p1) + (p2 + p3)) + ((p4 + p5) + (p6 + p7))) +
                          (((p8 + p9) + (pa + pb_)) + ((pc + pd) + (pe + pf)));
                    G0a = pkbf(p0, p1);  G0b = pkbf(p2, p3);
                    G1a = pkbf(p4, p5);  G1b = pkbf(p6, p7);
                    G2a = pkbf(p8, p9);  G2b = pkbf(pa, pb_);
                    G3a = pkbf(pc, pd);  G3b = pkbf(pe, pf);
                }

                // PV per 16-key step t: B[k=key][col=q].
                // permlane32_swap(a,b): a'=[a_lo,b_lo] (= word0), b'=[a_hi,b_hi] (= word2).
#pragma unroll
                for (int t = 0; t < 2; t++) {
                    u32 a0 = t ? G2a : G0a, b0 = t ? G3a : G1a;
                    u32 a1 = t ? G2b : G0b, b1 = t ? G3b : G1b;
                    plswap(a0, b0);   // a0 = w0, b0 = w2
                    plswap(a1, b1);   // a1 = w1, b1 = w3
                    u32x4 wv = {a0, a1, b0, b1};
                    bf16x8 pbf = __builtin_bit_cast(bf16x8, wv);

                    int kc = ktile * 32 + t * 16 + hi * 8;  // key col base in Vl
                    bf16x8 va0 = *(const bf16x8*)&Vl[(0 * 32 + l32) * VPAD + kc];
                    bf16x8 va1 = *(const bf16x8*)&Vl[(1 * 32 + l32) * VPAD + kc];
                    __builtin_amdgcn_s_setprio(1);
                    oacc0 = __builtin_amdgcn_mfma_f32_32x32x16_bf16(va0, pbf, oacc0, 0, 0, 0);
                    oacc1 = __builtin_amdgcn_mfma_f32_32x32x16_bf16(va1, pbf, oacc1, 0, 0, 0);
                    __builtin_amdgcn_s_setprio(0);
                }
            }
        }

        // epilogue: O^T[d][q=l32]; total row-sum = own half + partner half.
        float tot = rs + __shfl_xor(rs, 32);
        float inv = 1.0f / tot;
#pragma unroll
        for (int dt2 = 0; dt2 < 2; dt2++) {
#pragma unroll
            for (int rg = 0; rg < 4; rg++) {
                bf16x4 v4;
#pragma unroll
                for (int e = 0; e < 4; e++) {
                    float o = dt2 ? oacc1[rg * 4 + e] : oacc0[rg * 4 + e];
                    v4[e] = (__bf16)(o * inv);
                }
                int d = dt2 * 32 + 8 * rg + 4 * hi;
                *(bf16x4*)&Y[((size_t)(b * 2048 + qrow)) * 1024 + h * 64 + d] = v4;
            }
        }
    }
}

// ------------------------------- launcher ----------------------------------

extern "C" void kernel_launch(void* const* d_in, const int* in_sizes, int n_in,
                              void* d_out, int out_size, void* d_ws, size_t ws_size,
                              hipStream_t stream) {
    const float* x     = (const float*)d_in[0];
    const float* Wqkv  = (const float*)d_in[1];
    const float* bqkv  = (const float*)d_in[2];
    const float* Wproj = (const float*)d_in[3];
    const float* bproj = (const float*)d_in[4];
    float* out = (float*)d_out;

    __bf16* xb     = (__bf16*)d_ws;                       // 8192*1024
    __bf16* WqkvT  = xb + (size_t)BT * Cn;                // 3072*1024
    __bf16* WprojT = WqkvT + (size_t)N_QKV * Cn;          // 1024*1024
    __bf16* Qb     = WprojT + (size_t)Cn * Cn;            // [b][h][t][64], pre-scaled
    __bf16* Kb     = Qb + (size_t)BT * Cn;                // [b][h][t][64]
    __bf16* Vb     = Kb + (size_t)BT * Cn;                // [b][h][64][t] (transposed)
    __bf16* Yb     = Vb + (size_t)BT * Cn;                // 8192*1024

    int nx = BT * Cn;
    cast_x_kernel<<<(nx / 4 + 255) / 256, 256, 0, stream>>>(x, xb, nx);
    transpose_cast_kernel<<<dim3(N_QKV / 32, Cn / 32), 256, 0, stream>>>(Wqkv, WqkvT, Cn, N_QKV);
    transpose_cast_kernel<<<dim3(Cn / 32, Cn / 32), 256, 0, stream>>>(Wproj, WprojT, Cn, Cn);

    gemm_qkv_kernel<<<dim3(N_QKV / 128, BT / 128), 256, 0, stream>>>(
        xb, WqkvT, bqkv, Qb, Kb, Vb);

    attn_kernel<<<dim3(512), 256, 0, stream>>>(Qb, Kb, Vb, Yb);

    gemm_proj_kernel<<<dim3(Cn / 128, BT / 128), 256, 0, stream>>>(
        Yb, WprojT, bproj, out);
}